// Round 7
// baseline (254.572 us; speedup 1.0000x reference)
//
#include <hip/hip_runtime.h>

namespace {

typedef __attribute__((ext_vector_type(8)))  short          short8;
typedef __attribute__((ext_vector_type(8)))  unsigned short u16x8;
typedef __attribute__((ext_vector_type(4)))  unsigned short u16x4;
typedef __attribute__((ext_vector_type(4)))  float          f32x4;

constexpr int V   = 200;
constexpr int VP  = 208;   // v padded rows of B (13 x 16)
constexpr int UP  = 224;   // u padded cols of B (7 x 32)
constexpr int F   = 64;
constexpr int FO  = 64;
constexpr int NT  = 512;   // N*T

// ---- ws layout (bytes) ----
constexpr size_t WS_B1    = 0;                         // ushort [512][208][224] = 47,710,208
constexpr size_t WS_B2    = 47710208;                  // ushort [512][208][224] = 47,710,208
constexpr size_t WS_D     = 95420416;                  // float  [512][208] = 425,984 (atomic, memset 0)
constexpr size_t WS_SDIAG = 95846400;                  // float  [512][208] = 425,984
constexpr size_t WS_ADIAG = 96272384;                  // float  [8][208]   = 6,656
constexpr size_t WS_THT   = 96279040;                  // ushort [3][64][64] = 24,576

__device__ __forceinline__ unsigned short f2bf(float x) {
    union { float f; unsigned u; } c; c.f = x;
    unsigned r = c.u + 0x7FFF + ((c.u >> 16) & 1);
    return (unsigned short)(r >> 16);
}
__device__ __forceinline__ float bf2f(unsigned short h) {
    union { unsigned u; float f; } c; c.u = ((unsigned)h) << 16;
    return c.f;
}

// ============ P1: B1/B2 bf16 (off-diag coeffs; 0 on diagonal) + d + sdiag ====
// grid (512, 28): tile-pair (ti<=tj). Off-diag coeffs need only m and Att, so
// they can be produced here; the d-dependent diagonal stays fp32 in cheb_main.
__global__ __launch_bounds__(256)
void prep_B(const float* __restrict__ S,
            const float* __restrict__ Att,
            unsigned short* __restrict__ B1w,
            unsigned short* __restrict__ B2w,
            float* __restrict__ d_ws,
            float* __restrict__ sdiag)
{
    __shared__ float As[32][33];
    __shared__ float Bs[32][33];
    __shared__ float Ms[32][33];
    __shared__ float Aa[32][33];   // Att[32ti+r][32tj+c]
    __shared__ float Ab[32][33];   // Att[32tj+r][32ti+c]

    const int b   = blockIdx.x;
    const int n   = b >> 6;
    const int tid = threadIdx.x;
    int rem = blockIdx.y, ti = 0;
    while (rem >= 7 - ti) { rem -= 7 - ti; ++ti; }
    const int tj = ti + rem;
    const bool diag = (ti == tj);

    const float* __restrict__ Sp = S   + (size_t)b * (V * V);
    const float* __restrict__ Ap = Att + (size_t)n * (V * V);
    unsigned short* __restrict__ b1p = B1w + (size_t)b * (VP * UP);
    unsigned short* __restrict__ b2p = B2w + (size_t)b * (VP * UP);

    const int r  = tid >> 3;      // 0..31
    const int cg = tid & 7;       // 0..7
    const int c0 = 4 * cg;

    {
        const int gr = 32 * ti + r, gc = 32 * tj + c0;
        float4 a = make_float4(0.f, 0.f, 0.f, 0.f);
        float4 t = make_float4(0.f, 0.f, 0.f, 0.f);
        if (gr < V && gc < V) {
            a = *(const float4*)&Sp[gr * V + gc];
            t = *(const float4*)&Ap[gr * V + gc];
        }
        As[r][c0+0]=a.x; As[r][c0+1]=a.y; As[r][c0+2]=a.z; As[r][c0+3]=a.w;
        Aa[r][c0+0]=t.x; Aa[r][c0+1]=t.y; Aa[r][c0+2]=t.z; Aa[r][c0+3]=t.w;
        if (!diag) {
            const int hr = 32 * tj + r, hc = 32 * ti + c0;
            float4 bb = make_float4(0.f, 0.f, 0.f, 0.f);
            float4 tb = make_float4(0.f, 0.f, 0.f, 0.f);
            if (hr < V && hc < V) {
                bb = *(const float4*)&Sp[hr * V + hc];
                tb = *(const float4*)&Ap[hr * V + hc];
            }
            Bs[r][c0+0]=bb.x; Bs[r][c0+1]=bb.y; Bs[r][c0+2]=bb.z; Bs[r][c0+3]=bb.w;
            Ab[r][c0+0]=tb.x; Ab[r][c0+1]=tb.y; Ab[r][c0+2]=tb.z; Ab[r][c0+3]=tb.w;
        }
    }
    __syncthreads();

    // M[r][c] = min(S[v][u], S[u][v]); row-sum -> d[32ti+r]
    float m[4], rs = 0.f;
    #pragma unroll
    for (int e = 0; e < 4; ++e) {
        const int c = c0 + e;
        const float tw = diag ? As[c][r] : Bs[c][r];
        m[e] = fminf(As[r][c], tw);
        Ms[r][c] = m[e];
        rs += m[e];
    }
    rs += __shfl_xor(rs, 1); rs += __shfl_xor(rs, 2); rs += __shfl_xor(rs, 4);
    if (cg == 0 && 32 * ti + r < V)
        atomicAdd(&d_ws[b * VP + 32 * ti + r], rs);
    if (diag && cg == 0 && 32 * ti + r < V)
        sdiag[b * VP + 32 * ti + r] = As[r][r];
    __syncthreads();   // Ms complete

    if (!diag) {
        float ts = 0.f;
        #pragma unroll
        for (int e = 0; e < 4; ++e) ts += Ms[c0 + e][r];
        ts += __shfl_xor(ts, 1); ts += __shfl_xor(ts, 2); ts += __shfl_xor(ts, 4);
        if (cg == 0 && 32 * tj + r < V)
            atomicAdd(&d_ws[b * VP + 32 * tj + r], ts);
    }

    // orientation 1: rows v = 32ti+r, cols u = 32tj+c; att = Att[u][v]
    {
        const int vr = 32 * ti + r;
        if (vr < VP) {
            u16x4 w1, w2;
            #pragma unroll
            for (int e = 0; e < 4; ++e) {
                const int c = c0 + e;
                const float att = diag ? Aa[c][r] : Ab[c][r];
                const float mm  = Ms[r][c];
                const bool  dg  = diag && (c == r);
                w1[e] = dg ? (unsigned short)0 : f2bf(-mm * att);
                w2[e] = dg ? (unsigned short)0 : f2bf(2.0f * mm * mm * att);
            }
            *(u16x4*)&b1p[vr * UP + 32 * tj + c0] = w1;
            *(u16x4*)&b2p[vr * UP + 32 * tj + c0] = w2;
        }
    }
    // orientation 2 (off-diag): rows v = 32tj+r, cols u = 32ti+c; att = Att[u][v]
    if (!diag) {
        const int vr = 32 * tj + r;
        if (vr < VP) {
            u16x4 w1, w2;
            #pragma unroll
            for (int e = 0; e < 4; ++e) {
                const int c = c0 + e;
                const float att = Aa[c][r];
                const float mm  = Ms[c][r];
                w1[e] = f2bf(-mm * att);
                w2[e] = f2bf(2.0f * mm * mm * att);
            }
            *(u16x4*)&b1p[vr * UP + 32 * ti + c0] = w1;
            *(u16x4*)&b2p[vr * UP + 32 * ti + c0] = w2;
        }
    }
}

// ============ P2: Theta transpose (bf16) + Att diagonal ============
__global__ __launch_bounds__(256)
void prep_small(const float* __restrict__ Theta,
                const float* __restrict__ Att,
                unsigned short* __restrict__ thT,
                float* __restrict__ adiag)
{
    const int blk = blockIdx.x, tid = threadIdx.x;
    if (blk < 3) {
        __shared__ float T[64][65];
        for (int idx = tid; idx < 4096; idx += 256)
            T[idx >> 6][idx & 63] = Theta[blk * 4096 + idx];
        __syncthreads();
        for (int idx = tid; idx < 4096; idx += 256) {
            const int fo = idx >> 6, f = idx & 63;
            thT[blk * 4096 + fo * 64 + f] = f2bf(T[f][fo]);
        }
    } else {
        for (int idx = tid; idx < 8 * VP; idx += 256) {
            const int nn = idx / VP, v = idx % VP;
            adiag[idx] = (v < V) ? Att[(size_t)nn * (V * V) + v * V + v] : 0.f;
        }
    }
}

// ============ G: pure-GEMM K-loop + MFMA Theta epilogue, v-split x2 ============
constexpr int XT_S = 232;  // xsT stride (u16): 464 B = 16B-multiple, odd/2 banks ok
constexpr int A_S  = 40;   // B-tile stride (u16)
constexpr int YS_S = 72;   // ys / ThS stride (u16)

// LDS offsets (bytes)
constexpr int OFF_XST = 0;        // xsT [64][232] u16 = 29,696 | ys [112][72] u16
constexpr int OFF_B1  = 29696;    // B1s [112][40] u16 = 8,960 (pad 9,216) | ThS [64][72]
constexpr int OFF_B2  = 38912;    // B2s 9,216
constexpr int OFF_CB  = 48128;    // cbuf  [112] f32
constexpr int OFF_AD  = 48576;    // adbuf [112] f32
constexpr int SMEM_SZ = 49024;

__global__ __launch_bounds__(256, 3)
void cheb_main(const float* __restrict__ x,
               const unsigned short* __restrict__ thT,
               const unsigned short* __restrict__ B1w,
               const unsigned short* __restrict__ B2w,
               const float* __restrict__ d_ws,
               const float* __restrict__ sdiag,
               const float* __restrict__ adiag,
               float* __restrict__ out)
{
    __shared__ __align__(16) char smem[SMEM_SZ];
    unsigned short* xsT  = (unsigned short*)(smem + OFF_XST);
    unsigned short* B1s  = (unsigned short*)(smem + OFF_B1);
    unsigned short* B2s  = (unsigned short*)(smem + OFF_B2);
    unsigned short* ys   = (unsigned short*)(smem + OFF_XST);
    unsigned short* ThS  = (unsigned short*)(smem + OFF_B1);
    float*          cbuf = (float*)(smem + OFF_CB);
    float*         adbuf = (float*)(smem + OFF_AD);

    const int tid = threadIdx.x;
    const int b   = blockIdx.x;
    const int hv  = blockIdx.y;          // v-half: 0 -> tiles 0..6, 1 -> tiles 7..12
    const int n   = b >> 6;
    const int hvb   = 112 * hv;
    const int nrows = hv ? 96 : 112;

    const float* __restrict__ xp = x + (size_t)b * (V * F);
    const unsigned short* __restrict__ b1p = B1w + (size_t)b * (VP * UP);
    const unsigned short* __restrict__ b2p = B2w + (size_t)b * (VP * UP);
    float* __restrict__ op = out + (size_t)b * (V * FO);

    // ---- stage x -> bf16 xsT[f][u] (transposed; zeros for u >= 200) ----
    for (int idx = tid; idx < UP * 16; idx += 256) {
        const int u = idx >> 4, fg = idx & 15;
        float4 v = make_float4(0.f, 0.f, 0.f, 0.f);
        if (u < V) v = *(const float4*)&xp[u * F + 4 * fg];
        xsT[(4 * fg + 0) * XT_S + u] = f2bf(v.x);
        xsT[(4 * fg + 1) * XT_S + u] = f2bf(v.y);
        xsT[(4 * fg + 2) * XT_S + u] = f2bf(v.z);
        xsT[(4 * fg + 3) * XT_S + u] = f2bf(v.w);
    }
    if (tid < nrows) {
        const int g = hvb + tid;
        cbuf[tid]  = d_ws[b * VP + g] - 1.0f - sdiag[b * VP + g];  // c = d-1-S_vv
        adbuf[tid] = adiag[n * VP + g];
    }

    const int wave = tid >> 6, lane = tid & 63;
    const int q = lane >> 4, ln = lane & 15;
    // hv0: 7 tiles -> 2/2/2/1 per wave; hv1: 6 tiles -> 2/2/1/1
    const int myBase = (hv == 0) ? 2 * wave : ((wave < 2) ? 2 * wave : wave + 2);
    const int myCnt  = (hv == 0) ? ((wave == 3) ? 1 : 2) : ((wave < 2) ? 2 : 1);

    f32x4 acc1[2][4], acc2[2][4];
    #pragma unroll
    for (int i = 0; i < 2; ++i)
        #pragma unroll
        for (int j = 0; j < 4; ++j) { acc1[i][j] = (f32x4)0.f; acc2[i][j] = (f32x4)0.f; }

    // ---- register prefetch of next B chunk (no conversion math anymore) ----
    u16x8 pf1[2], pf2[2];
    const int nch = nrows * 4;    // 16B chunks per matrix per kt
    auto load_chunks = [&](int kt) {
        const int u0 = 32 * kt;
        #pragma unroll
        for (int c = 0; c < 2; ++c) {
            const int idx = tid + 256 * c;
            if (idx < nch) {
                const int row = idx >> 2, ch = idx & 3;
                const size_t off = (size_t)(hvb + row) * UP + u0 + 8 * ch;
                pf1[c] = *(const u16x8*)&b1p[off];
                pf2[c] = *(const u16x8*)&b2p[off];
            }
        }
    };
    load_chunks(0);

    // ---- K loop: 7 x 32 u's; pure stage->MFMA ----
    for (int kt = 0; kt < 7; ++kt) {
        const int u0 = 32 * kt;
        __syncthreads();
        #pragma unroll
        for (int c = 0; c < 2; ++c) {
            const int idx = tid + 256 * c;
            if (idx < nch) {
                const int row = idx >> 2, ch = idx & 3;
                *(u16x8*)&B1s[row * A_S + 8 * ch] = pf1[c];
                *(u16x8*)&B2s[row * A_S + 8 * ch] = pf2[c];
            }
        }
        if (kt < 6) load_chunks(kt + 1);
        __syncthreads();
        short8 bfr[4];
        #pragma unroll
        for (int ft = 0; ft < 4; ++ft)
            bfr[ft] = *(const short8*)&xsT[(16 * ft + ln) * XT_S + u0 + 8 * q];
        #pragma unroll
        for (int vi = 0; vi < 2; ++vi) {
            if (vi < myCnt) {
                const int row = (myBase + vi) * 16 + ln;
                const short8 af1 = *(const short8*)&B1s[row * A_S + 8 * q];
                const short8 af2 = *(const short8*)&B2s[row * A_S + 8 * q];
                #pragma unroll
                for (int ft = 0; ft < 4; ++ft) {
                    acc1[vi][ft] = __builtin_amdgcn_mfma_f32_16x16x32_bf16(af1, bfr[ft], acc1[vi][ft], 0, 0, 0);
                    acc2[vi][ft] = __builtin_amdgcn_mfma_f32_16x16x32_bf16(af2, bfr[ft], acc2[vi][ft], 0, 0, 0);
                }
            }
        }
    }

    // ---- epilogue: out-tiles += mfma(ys_k, ThT_k), k = 1, 2, 0 ----
    f32x4 ot[2][4];
    #pragma unroll
    for (int i = 0; i < 2; ++i)
        #pragma unroll
        for (int j = 0; j < 4; ++j) ot[i][j] = (f32x4)0.f;

    #pragma unroll
    for (int pass = 0; pass < 3; ++pass) {
        const int k = (pass == 0) ? 1 : (pass == 1) ? 2 : 0;
        __syncthreads();

        if (k == 0) {
            for (int idx = tid; idx < nrows * 16; idx += 256) {
                const int vloc = idx >> 4, fg = idx & 15;
                const int v = hvb + vloc;
                u16x4 w; w[0] = 0; w[1] = 0; w[2] = 0; w[3] = 0;
                if (v < V) {
                    const float av = adbuf[vloc];
                    const float4 xv = *(const float4*)&xp[v * F + 4 * fg];
                    w[0] = f2bf(av * xv.x); w[1] = f2bf(av * xv.y);
                    w[2] = f2bf(av * xv.z); w[3] = f2bf(av * xv.w);
                }
                *(u16x4*)&ys[vloc * YS_S + 4 * fg] = w;
            }
        } else {
            #pragma unroll
            for (int vi = 0; vi < 2; ++vi) {
                if (vi < myCnt) {
                    const int row16 = (myBase + vi) * 16;
                    #pragma unroll
                    for (int ft = 0; ft < 4; ++ft) {
                        const f32x4 a = (k == 1) ? acc1[vi][ft] : acc2[vi][ft];
                        #pragma unroll
                        for (int reg = 0; reg < 4; ++reg) {
                            const int vloc = row16 + 4 * q + reg;
                            const int v = hvb + vloc;
                            float val = 0.f;
                            if (v < V) {
                                const float cc = cbuf[vloc];
                                const float dc = ((k == 1) ? cc : (2.0f * cc * cc - 1.0f)) * adbuf[vloc];
                                val = a[reg] + dc * xp[v * F + 16 * ft + ln];
                            }
                            ys[vloc * YS_S + 16 * ft + ln] = f2bf(val);
                        }
                    }
                }
            }
        }
        for (int idx = tid; idx < 64 * 8; idx += 256) {
            const int fo = idx >> 3, ch = idx & 7;
            *(u16x8*)&ThS[fo * YS_S + 8 * ch] =
                *(const u16x8*)&thT[k * 4096 + fo * 64 + 8 * ch];
        }
        __syncthreads();
        #pragma unroll
        for (int vi = 0; vi < 2; ++vi) {
            if (vi < myCnt) {
                const int vrow = (myBase + vi) * 16 + ln;
                #pragma unroll
                for (int ks = 0; ks < 2; ++ks) {
                    const short8 af = *(const short8*)&ys[vrow * YS_S + 32 * ks + 8 * q];
                    #pragma unroll
                    for (int fot = 0; fot < 4; ++fot) {
                        const short8 bf = *(const short8*)&ThS[(16 * fot + ln) * YS_S + 32 * ks + 8 * q];
                        ot[vi][fot] = __builtin_amdgcn_mfma_f32_16x16x32_bf16(af, bf, ot[vi][fot], 0, 0, 0);
                    }
                }
            }
        }
    }

    // ---- relu + store ----
    #pragma unroll
    for (int vi = 0; vi < 2; ++vi) {
        if (vi < myCnt) {
            const int row16 = (myBase + vi) * 16;
            #pragma unroll
            for (int fot = 0; fot < 4; ++fot) {
                #pragma unroll
                for (int reg = 0; reg < 4; ++reg) {
                    const int v = hvb + row16 + 4 * q + reg;
                    if (v < V)
                        op[v * FO + 16 * fot + ln] = fmaxf(ot[vi][fot][reg], 0.f);
                }
            }
        }
    }
}

} // namespace

extern "C" void kernel_launch(void* const* d_in, const int* in_sizes, int n_in,
                              void* d_out, int out_size, void* d_ws, size_t ws_size,
                              hipStream_t stream) {
    const float* x     = (const float*)d_in[0];
    const float* Att   = (const float*)d_in[1];
    const float* S     = (const float*)d_in[2];
    const float* Theta = (const float*)d_in[3];
    float* out         = (float*)d_out;

    char* ws = (char*)d_ws;
    unsigned short* B1w = (unsigned short*)(ws + WS_B1);
    unsigned short* B2w = (unsigned short*)(ws + WS_B2);
    float* d_sum = (float*)(ws + WS_D);
    float* sdiag = (float*)(ws + WS_SDIAG);
    float* adiag = (float*)(ws + WS_ADIAG);
    unsigned short* thT = (unsigned short*)(ws + WS_THT);

    // d accumulates via atomicAdd -> must start at 0 every call
    hipMemsetAsync(d_sum, 0, (size_t)NT * VP * sizeof(float), stream);

    hipLaunchKernelGGL(prep_B,     dim3(NT, 28), dim3(256), 0, stream, S, Att, B1w, B2w, d_sum, sdiag);
    hipLaunchKernelGGL(prep_small, dim3(4),      dim3(256), 0, stream, Theta, Att, thT, adiag);
    hipLaunchKernelGGL(cheb_main,  dim3(NT, 2),  dim3(256), 0, stream,
                       x, thT, B1w, B2w, d_sum, sdiag, adiag, out);
}